// Round 3
// baseline (330.553 us; speedup 1.0000x reference)
//
#include <hip/hip_runtime.h>
#include <hip/hip_bf16.h>

// MoE: N=16384 tokens, D=1024, E=8 experts, top-2 routing.
// R8: moe_gemm staging switched from global_load_lds to REG-STAGING (T14):
// global_load_dwordx4 -> VGPR -> ds_write_b128. Rationale: LLVM's waitcnt pass
// conservatively inserts s_waitcnt vmcnt(0) before ds_reads that may alias LDS
// written by global_load_lds, draining the prefetch every read cluster and
// exposing full gather latency per K-tile (R5/R6/R7 all ~5400 cy/K-tile
// regardless of schedule). Reg-staging has no such hazard: ds_write->ds_read
// orders via lgkmcnt; loads for tile t+1 issue BEFORE tile t's compute
// (issue-early/write-late), so compute covers L3/HBM gather latency.
// One raw s_barrier per K-tile (manual lgkmcnt(0), no implicit vmcnt(0)).
// Geometry/swizzle from R6/R7: 192x256 tile, BK=64, 8 waves (2x4) of 96x64,
// XOR chunk swizzle (same mapping, now applied on the reg-staged ds_write's
// global source), 112 KB double-buffered LDS.
// Router/scan/scatter/combine unchanged.

constexpr int DIMS = 1024;
constexpr int NE   = 8;
constexpr int ROUTER_BLOCKS = 1024;           // 16 tokens per block
constexpr int WCONV_BLOCKS  = NE * DIMS * DIMS / (8 * 256);  // 4096
constexpr int BM = 192, BN = 256, BK = 64;
constexpr int RT_PER_XCD = 23;   // 23*8=184 >= worst-case sum ceil(cnt/192)=178

typedef __attribute__((ext_vector_type(8))) short short8;
typedef __attribute__((ext_vector_type(4))) short short4_t;
typedef __attribute__((ext_vector_type(4))) float f32x4;

__device__ __forceinline__ float b2f(unsigned short u) {
  union { unsigned int i; float f; } x; x.i = ((unsigned)u) << 16; return x.f;
}
__device__ __forceinline__ short f2bs(float f) {
  __hip_bfloat16 h = __float2bfloat16(f);
  return *(short*)&h;
}

// ---------------- prep: router blocks [0,1024) + wconv blocks [1024,5120) ----
// wconv writes wb ROW-MAJOR [e][o][d] bf16 (fully coalesced streaming cvt).
// router: NO global atomics — writes per-block counts + per-slot meta.
__global__ __launch_bounds__(256) void prep_kernel(
    const float* __restrict__ x, const float* __restrict__ rw,
    const float* __restrict__ rb, const float* __restrict__ ew,
    __hip_bfloat16* __restrict__ xb, __hip_bfloat16* __restrict__ wb,
    int* __restrict__ blk_cnt, int* __restrict__ tmp_meta,
    float* __restrict__ tmp_gate, int n_tok) {
  const int tid = threadIdx.x;

  if ((int)blockIdx.x >= ROUTER_BLOCKS) {
    unsigned g = (unsigned)(blockIdx.x - ROUTER_BLOCKS) * 256 + tid;  // 8-elem chunk
    const float4* src = (const float4*)(ew + (size_t)g * 8);
    float4 a = src[0], b = src[1];
    union { __hip_bfloat16 h[8]; float4 f; } u;
    u.h[0] = __float2bfloat16(a.x); u.h[1] = __float2bfloat16(a.y);
    u.h[2] = __float2bfloat16(a.z); u.h[3] = __float2bfloat16(a.w);
    u.h[4] = __float2bfloat16(b.x); u.h[5] = __float2bfloat16(b.y);
    u.h[6] = __float2bfloat16(b.z); u.h[7] = __float2bfloat16(b.w);
    ((float4*)wb)[g] = u.f;
    return;
  }

  // ---- router role: 16 tokens/block, wave-per-token, float4 vectorized ----
  __shared__ float s_rw[NE * DIMS];   // 32 KB
  __shared__ int s_cnt[NE];
  __shared__ int s_e[32];
  __shared__ float s_g[32];
  __shared__ int s_pos[32];

  const float4* rw4g = (const float4*)rw;
  float4* s4 = (float4*)s_rw;
  for (int i = tid; i < NE * DIMS / 4; i += 256) s4[i] = rw4g[i];
  if (tid < NE) s_cnt[tid] = 0;
  __syncthreads();

  const float4* s_rw4 = (const float4*)s_rw;
  const int wave = tid >> 6, lane = tid & 63;
  for (int i = 0; i < 4; ++i) {
    int t = blockIdx.x * 16 + wave * 4 + i;
    const float4* xr = (const float4*)(x + (size_t)t * DIMS);
    short4_t* xw = (short4_t*)(xb + (size_t)t * DIMS);
    float a[NE];
#pragma unroll
    for (int e = 0; e < NE; ++e) a[e] = 0.f;
#pragma unroll
    for (int j = 0; j < 4; ++j) {
      float4 v = xr[lane + j * 64];
      short4_t p;
      p[0] = f2bs(v.x); p[1] = f2bs(v.y); p[2] = f2bs(v.z); p[3] = f2bs(v.w);
      xw[lane + j * 64] = p;
#pragma unroll
      for (int e = 0; e < NE; ++e) {
        float4 w = s_rw4[e * 256 + lane + j * 64];
        a[e] = fmaf(v.x, w.x, fmaf(v.y, w.y, fmaf(v.z, w.z, fmaf(v.w, w.w, a[e]))));
      }
    }
#pragma unroll
    for (int off = 32; off > 0; off >>= 1) {
#pragma unroll
      for (int e = 0; e < NE; ++e) a[e] += __shfl_xor(a[e], off, 64);
    }
    if (lane == 0) {
      float l[NE];
#pragma unroll
      for (int e = 0; e < NE; ++e) l[e] = a[e] + rb[e];
      int e0 = 0;
#pragma unroll
      for (int e = 1; e < NE; ++e) if (l[e] > l[e0]) e0 = e;
      int e1 = (e0 == 0) ? 1 : 0;
#pragma unroll
      for (int e = 0; e < NE; ++e) if (e != e0 && l[e] > l[e1]) e1 = e;
      float r = expf(l[e1] - l[e0]);   // <= 1
      float g0 = 1.f / (1.f + r);
      float g1 = 1.f - g0;
      int ai = (wave * 4 + i) * 2;
      int p0 = atomicAdd(&s_cnt[e0], 1);   // LDS atomic only
      int p1 = atomicAdd(&s_cnt[e1], 1);
      s_e[ai] = e0; s_g[ai] = g0; s_pos[ai] = p0;
      s_e[ai + 1] = e1; s_g[ai + 1] = g1; s_pos[ai + 1] = p1;
    }
  }
  __syncthreads();
  if (tid < NE) blk_cnt[blockIdx.x * NE + tid] = s_cnt[tid];
  if (tid < 32) {
    int s = blockIdx.x * 32 + tid;
    tmp_meta[s] = s_e[tid] | (s_pos[tid] << 3);
    tmp_gate[s] = s_g[tid];
  }
}

// ---------------- scan: exclusive prefix of blk_cnt per expert ----------------
__global__ __launch_bounds__(512) void scan_kernel(
    const int* __restrict__ blk_cnt, int* __restrict__ blk_base,
    int* __restrict__ counts) {
  const int e = threadIdx.x >> 6, lane = threadIdx.x & 63;
  int running = 0;
  for (int c = 0; c < ROUTER_BLOCKS / 64; ++c) {
    int v = blk_cnt[(c * 64 + lane) * NE + e];
    int incl = v;
#pragma unroll
    for (int off = 1; off < 64; off <<= 1) {
      int t = __shfl_up(incl, off, 64);
      if (lane >= off) incl += t;
    }
    blk_base[(c * 64 + lane) * NE + e] = running + incl - v;
    running += __shfl(incl, 63, 64);
  }
  if (lane == 0) counts[e] = running;
}

// ---------------- scatter: place entries/gates ----------------
__global__ __launch_bounds__(256) void scatter_kernel(
    const int* __restrict__ tmp_meta, const float* __restrict__ tmp_gate,
    const int* __restrict__ blk_base, int* __restrict__ entries,
    float* __restrict__ gates, int n_tok) {
  int s = blockIdx.x * 256 + threadIdx.x;       // slot in [0, 2*n_tok)
  int meta = tmp_meta[s];
  int e = meta & 7, pos = meta >> 3;
  int p = blk_base[(s >> 5) * NE + e] + pos;
  entries[e * n_tok + p] = ((s >> 1) << 1) | (s & 1);   // token*2 + slot parity
  gates[e * n_tok + p] = tmp_gate[s];
}

// ---------------- grouped gathered GEMM ----------------
// 192x256 tile, BK=64; 8 waves (2x4) of 96x64 = 6x4 of 16x16x32 bf16.
// LDS: As[2][192*64] (24KB ea) + Bs[2][256*64] (32KB ea) = 112KB -> 1 block/CU.
// Per K-tile: [vmcnt-counted wait via reg dep] 7x ds_write_b128 (tile kt) ->
// issue 7x global_load_dwordx4 (tile kt+1) -> lgkmcnt(0) -> s_barrier ->
// compute 48 MFMA from buf[kt&1] in 2 ks-clusters (compiler-scheduled lgkm).
// ONE barrier per K-tile: WAR on buf[(kt+1)&1] is safe because every wave
// passing barrier(kt) has finished compute(kt-1) in program order.
__global__ __launch_bounds__(512, 2) void moe_gemm(
    const __hip_bfloat16* __restrict__ xb, const __hip_bfloat16* __restrict__ wb,
    const float* __restrict__ eb, const int* __restrict__ counts,
    const int* __restrict__ entries, const float* __restrict__ gates,
    __hip_bfloat16* __restrict__ y, int n_tok) {
  const int xcd = blockIdx.x & 7;
  const int j = blockIdx.x >> 3;                  // [0, 92)
  const int ct = j & 3;
  const int virt = xcd * RT_PER_XCD + (j >> 2);   // virtual row-tile id

  int e = -1, rt = 0, cnt = 0, acc_t = 0;
#pragma unroll
  for (int i = 0; i < NE; ++i) {
    int c = counts[i];
    int t = (c + BM - 1) / BM;
    if (e < 0 && virt < acc_t + t) { e = i; rt = virt - acc_t; cnt = c; }
    acc_t += t;
  }
  if (e < 0) return;

  __shared__ __align__(16) char smem[2 * 24576 + 2 * 32768];  // 112 KB

  const int tid = threadIdx.x;
  const int l = tid & 63, w = tid >> 6;
  const int row0 = rt * BM;
  const int n0 = ct * BN;

  // ---- staging source pointers (pre-swizzled chunk within 8-chunk row) ----
  // Thread (w,l), slot i -> LDS row R=(i*8+w)*8+(l>>3), physical chunk c=l&7.
  // Physical chunk c of row R holds logical chunk c^(R&7) = (l&7)^(l>>3)&7.
  const int qsw = (l & 7) ^ ((l >> 3) & 7);
  const __hip_bfloat16* aptr[3];
  const __hip_bfloat16* bptr[4];
#pragma unroll
  for (int i = 0; i < 3; ++i) {
    int R = (i * 8 + w) * 8 + (l >> 3);           // [0,192)
    int gr = row0 + R;
    int ent = (gr < cnt) ? entries[e * n_tok + gr] : 0;
    aptr[i] = xb + (size_t)(ent >> 1) * DIMS + qsw * 8;
  }
#pragma unroll
  for (int i = 0; i < 4; ++i) {
    int R = (i * 8 + w) * 8 + (l >> 3);           // [0,256)
    bptr[i] = wb + ((size_t)e << 20) + (size_t)(n0 + R) * DIMS + qsw * 8;
  }

  // ---- LDS write addresses (linear, 16B per thread per slot) ----
  char* awr[3];
  char* bwr[4];
#pragma unroll
  for (int i = 0; i < 3; ++i) awr[i] = smem + (i * 8 + w) * 1024 + l * 16;
#pragma unroll
  for (int i = 0; i < 4; ++i) bwr[i] = smem + 49152 + (i * 8 + w) * 1024 + l * 16;

  // ---- fragment read offsets (bytes within a buffer) ----
  const int fr = l & 15, quad = l >> 4;
  const int wr = w >> 2, wc = w & 3;              // 2 x 4 wave grid
  const int swz = (quad ^ (fr & 7)) << 4;         // chunk XOR on read side
  const int aoff0 = (wr * 96 + fr) * 128 + swz;   // + mt*2048; ks=1: ^64
  const int boff0 = (wc * 64 + fr) * 128 + swz;   // + nt*2048; ks=1: ^64

  f32x4 acc[6][4] = {};
  float4 ra[3], rb4[4];

  // prologue: load tile 0 into registers
#pragma unroll
  for (int i = 0; i < 3; ++i) ra[i] = *(const float4*)(aptr[i]);
#pragma unroll
  for (int i = 0; i < 4; ++i) rb4[i] = *(const float4*)(bptr[i]);

#pragma unroll 1
  for (int kt = 0; kt < 16; ++kt) {
    const int cur = kt & 1;
    const int bufo = cur * 24576;
    const int bufb = cur * 32768;
    // ---- write tile kt to LDS (compiler inserts counted vmcnt for ra/rb4) ----
#pragma unroll
    for (int i = 0; i < 3; ++i) *(float4*)(awr[i] + bufo) = ra[i];
#pragma unroll
    for (int i = 0; i < 4; ++i) *(float4*)(bwr[i] + bufb) = rb4[i];
    // ---- issue tile kt+1 loads (in flight across the whole compute) ----
    if (kt < 15) {
      const int koff = (kt + 1) * 64;
#pragma unroll
      for (int i = 0; i < 3; ++i) ra[i] = *(const float4*)(aptr[i] + koff);
#pragma unroll
      for (int i = 0; i < 4; ++i) rb4[i] = *(const float4*)(bptr[i] + koff);
    }
    asm volatile("s_waitcnt lgkmcnt(0)" ::: "memory");   // my ds_writes done
    __builtin_amdgcn_s_barrier();                        // all waves staged
    __builtin_amdgcn_sched_barrier(0);

    // ---- compute: 2 ks-clusters of 24 MFMA ----
    const char* As = smem + bufo;
    const char* Bs = smem + 49152 + bufb;
    short8 af[6], bf[4];
#pragma unroll
    for (int mt = 0; mt < 6; ++mt) af[mt] = *(const short8*)(As + aoff0 + mt * 2048);
#pragma unroll
    for (int nt = 0; nt < 4; ++nt) bf[nt] = *(const short8*)(Bs + boff0 + nt * 2048);
    __builtin_amdgcn_s_setprio(1);
#pragma unroll
    for (int mt = 0; mt < 6; ++mt)
#pragma unroll
      for (int nt = 0; nt < 4; ++nt)
        acc[mt][nt] = __builtin_amdgcn_mfma_f32_16x16x32_bf16(af[mt], bf[nt], acc[mt][nt], 0, 0, 0);
    __builtin_amdgcn_s_setprio(0);
    short8 af2[6], bf2[4];
#pragma unroll
    for (int mt = 0; mt < 6; ++mt) af2[mt] = *(const short8*)(As + ((aoff0 + mt * 2048) ^ 64));
#pragma unroll
    for (int nt = 0; nt < 4; ++nt) bf2[nt] = *(const short8*)(Bs + ((boff0 + nt * 2048) ^ 64));
    __builtin_amdgcn_s_setprio(1);
#pragma unroll
    for (int mt = 0; mt < 6; ++mt)
#pragma unroll
      for (int nt = 0; nt < 4; ++nt)
        acc[mt][nt] = __builtin_amdgcn_mfma_f32_16x16x32_bf16(af2[mt], bf2[nt], acc[mt][nt], 0, 0, 0);
    __builtin_amdgcn_s_setprio(0);
    // no end barrier: next iteration's ds_write targets the other buffer, and
    // barrier(kt+1) orders it against compute(kt) in program order per wave.
  }

  // ---- epilogue: C/D layout col=lane&15, row=(lane>>4)*4+reg ----
  float bias[4];
#pragma unroll
  for (int nt = 0; nt < 4; ++nt) bias[nt] = eb[e * DIMS + n0 + wc * 64 + nt * 16 + fr];
#pragma unroll
  for (int mt = 0; mt < 6; ++mt) {
#pragma unroll
    for (int r = 0; r < 4; ++r) {
      int m = wr * 96 + mt * 16 + quad * 4 + r;
      int gr = row0 + m;
      if (gr < cnt) {
        int ent = entries[e * n_tok + gr];
        float g = gates[e * n_tok + gr];
        __hip_bfloat16* yp = y + (size_t)ent * DIMS + n0 + wc * 64 + fr;
#pragma unroll
        for (int nt = 0; nt < 4; ++nt)
          yp[nt * 16] = __float2bfloat16(g * (acc[mt][nt][r] + bias[nt]));
      }
    }
  }
}

// ---------------- combine: out[n] = y[n,0] + y[n,1] ----------------
__global__ __launch_bounds__(256) void combine_kernel(const __hip_bfloat16* __restrict__ y,
                                                      float* __restrict__ out) {
  size_t idx = (size_t)blockIdx.x * 256 + threadIdx.x;  // one 8-wide chunk
  size_t n = idx >> 7;
  int c = (int)(idx & 127) << 3;
  short8 v0 = *(const short8*)(y + (n * 2) * DIMS + c);
  short8 v1 = *(const short8*)(y + (n * 2 + 1) * DIMS + c);
  float4 o0, o1;
  o0.x = b2f((unsigned short)v0[0]) + b2f((unsigned short)v1[0]);
  o0.y = b2f((unsigned short)v0[1]) + b2f((unsigned short)v1[1]);
  o0.z = b2f((unsigned short)v0[2]) + b2f((unsigned short)v1[2]);
  o0.w = b2f((unsigned short)v0[3]) + b2f((unsigned short)v1[3]);
  o1.x = b2f((unsigned short)v0[4]) + b2f((unsigned short)v1[4]);
  o1.y = b2f((unsigned short)v0[5]) + b2f((unsigned short)v1[5]);
  o1.z = b2f((unsigned short)v0[6]) + b2f((unsigned short)v1[6]);
  o1.w = b2f((unsigned short)v0[7]) + b2f((unsigned short)v1[7]);
  float* op = out + n * DIMS + c;
  ((float4*)op)[0] = o0;
  ((float4*)op)[1] = o1;
}

extern "C" void kernel_launch(void* const* d_in, const int* in_sizes, int n_in,
                              void* d_out, int out_size, void* d_ws, size_t ws_size,
                              hipStream_t stream) {
  const float* x  = (const float*)d_in[0];
  const float* rw = (const float*)d_in[1];
  const float* rb = (const float*)d_in[2];
  const float* ew = (const float*)d_in[3];
  const float* eb = (const float*)d_in[4];
  float* out = (float*)d_out;
  const int n_tok = in_sizes[0] / DIMS;  // 16384
  const int n_slot = 2 * n_tok;

  // workspace layout
  char* ws = (char*)d_ws;
  size_t off = 0;
  int* counts = (int*)ws;                      off += 256;
  int* blk_cnt = (int*)(ws + off);             off += (size_t)ROUTER_BLOCKS * NE * 4;
  int* blk_base = (int*)(ws + off);            off += (size_t)ROUTER_BLOCKS * NE * 4;
  int* tmp_meta = (int*)(ws + off);            off += (size_t)n_slot * 4;
  float* tmp_gate = (float*)(ws + off);        off += (size_t)n_slot * 4;
  __hip_bfloat16* xb = (__hip_bfloat16*)(ws + off); off += (size_t)n_tok * DIMS * 2;
  __hip_bfloat16* wb = (__hip_bfloat16*)(ws + off); off += (size_t)NE * DIMS * DIMS * 2;
  int*   entries = (int*)(ws + off);           off += (size_t)NE * n_tok * 4;
  float* gates   = (float*)(ws + off);         off += (size_t)NE * n_tok * 4;
  __hip_bfloat16* y = (__hip_bfloat16*)(ws + off); off += (size_t)n_slot * DIMS * 2;
  if (ws_size < off) return;  // signature: output stays exactly zero

  prep_kernel<<<ROUTER_BLOCKS + WCONV_BLOCKS, 256, 0, stream>>>(
      x, rw, rb, ew, xb, wb, blk_cnt, tmp_meta, tmp_gate, n_tok);
  scan_kernel<<<1, 512, 0, stream>>>(blk_cnt, blk_base, counts);
  scatter_kernel<<<n_slot / 256, 256, 0, stream>>>(
      tmp_meta, tmp_gate, blk_base, entries, gates, n_tok);
  moe_gemm<<<8 * RT_PER_XCD * 4, 512, 0, stream>>>(
      xb, wb, eb, counts, entries, gates, y, n_tok);
  combine_kernel<<<(unsigned)((size_t)n_tok * DIMS / 8 / 256), 256, 0, stream>>>(y, out);
}

// Round 4
// 292.172 us; speedup vs baseline: 1.1314x; 1.1314x over previous
//
#include <hip/hip_runtime.h>
#include <hip/hip_bf16.h>

// MoE: N=16384 tokens, D=1024, E=8 experts, top-2 routing.
// R9: moe_gemm = faithful m201-rhythm fine-phase schedule on a 256x128 tile.
// BK=64, 8 waves (4M x 2N) of 64x64 each; 96 KB LDS double-buffer; chunk-XOR
// swizzle (verified 0-conflict in R7). Per K-tile, 2 phases of 16 MFMA:
//  ph0: 12 ds_read (A all frags + B nt01) || stage B(t+1) [2 gload_lds]
//       -> bar -> lgkm(0)+schedbar -> prio1 16 MFMA prio0 -> bar
//  ph1: 4 ds_read (B nt23)            || stage A(t+2) [4 gload_lds]
//       -> bar -> lgkm(0)+schedbar -> prio1 16 MFMA prio0 -> vmcnt(4) -> bar
// Staging is SPREAD across phases (m196: burst staging without the fine
// interleave is the documented -7..-27% variant; R5/R6/R7 all sat at the
// documented 2-phase plateau ~610-680 TF). vmcnt(4) retires exactly tile
// t+1's 6 loads (queue = [A(t+1):4][B(t+1):2][A(t+2):4]); never drains to 0
// in steady state (T4). Region safety: stage A(t+2) overwrites buf[cur].A
// only after ph0's end-barrier (all waves' A reads landed at their lgkm(0)
// before that barrier); stage B(t+1) targets the other buffer.
// Router/scan/scatter/combine unchanged from the 103 us config.

constexpr int DIMS = 1024;
constexpr int NE   = 8;
constexpr int ROUTER_BLOCKS = 1024;           // 16 tokens per block
constexpr int WCONV_BLOCKS  = NE * DIMS * DIMS / (8 * 256);  // 4096
constexpr int BM = 256, BN = 128, BK = 64;
constexpr int RT_PER_XCD = 17;   // 17*8=136 >= max sum ceil(cnt_e/256)=135

typedef __attribute__((ext_vector_type(8))) short short8;
typedef __attribute__((ext_vector_type(4))) short short4_t;
typedef __attribute__((ext_vector_type(4))) float f32x4;

typedef const __attribute__((address_space(1))) void* gp_t;
typedef __attribute__((address_space(3))) void* sp_t;

__device__ __forceinline__ float b2f(unsigned short u) {
  union { unsigned int i; float f; } x; x.i = ((unsigned)u) << 16; return x.f;
}
__device__ __forceinline__ short f2bs(float f) {
  __hip_bfloat16 h = __float2bfloat16(f);
  return *(short*)&h;
}

// ---------------- prep: router blocks [0,1024) + wconv blocks [1024,5120) ----
// wconv writes wb ROW-MAJOR [e][o][d] bf16 (fully coalesced streaming cvt).
// router: NO global atomics — writes per-block counts + per-slot meta.
__global__ __launch_bounds__(256) void prep_kernel(
    const float* __restrict__ x, const float* __restrict__ rw,
    const float* __restrict__ rb, const float* __restrict__ ew,
    __hip_bfloat16* __restrict__ xb, __hip_bfloat16* __restrict__ wb,
    int* __restrict__ blk_cnt, int* __restrict__ tmp_meta,
    float* __restrict__ tmp_gate, int n_tok) {
  const int tid = threadIdx.x;

  if ((int)blockIdx.x >= ROUTER_BLOCKS) {
    unsigned g = (unsigned)(blockIdx.x - ROUTER_BLOCKS) * 256 + tid;  // 8-elem chunk
    const float4* src = (const float4*)(ew + (size_t)g * 8);
    float4 a = src[0], b = src[1];
    union { __hip_bfloat16 h[8]; float4 f; } u;
    u.h[0] = __float2bfloat16(a.x); u.h[1] = __float2bfloat16(a.y);
    u.h[2] = __float2bfloat16(a.z); u.h[3] = __float2bfloat16(a.w);
    u.h[4] = __float2bfloat16(b.x); u.h[5] = __float2bfloat16(b.y);
    u.h[6] = __float2bfloat16(b.z); u.h[7] = __float2bfloat16(b.w);
    ((float4*)wb)[g] = u.f;
    return;
  }

  // ---- router role: 16 tokens/block, wave-per-token, float4 vectorized ----
  __shared__ float s_rw[NE * DIMS];   // 32 KB
  __shared__ int s_cnt[NE];
  __shared__ int s_e[32];
  __shared__ float s_g[32];
  __shared__ int s_pos[32];

  const float4* rw4g = (const float4*)rw;
  float4* s4 = (float4*)s_rw;
  for (int i = tid; i < NE * DIMS / 4; i += 256) s4[i] = rw4g[i];
  if (tid < NE) s_cnt[tid] = 0;
  __syncthreads();

  const float4* s_rw4 = (const float4*)s_rw;
  const int wave = tid >> 6, lane = tid & 63;
  for (int i = 0; i < 4; ++i) {
    int t = blockIdx.x * 16 + wave * 4 + i;
    const float4* xr = (const float4*)(x + (size_t)t * DIMS);
    short4_t* xw = (short4_t*)(xb + (size_t)t * DIMS);
    float a[NE];
#pragma unroll
    for (int e = 0; e < NE; ++e) a[e] = 0.f;
#pragma unroll
    for (int j = 0; j < 4; ++j) {
      float4 v = xr[lane + j * 64];
      short4_t p;
      p[0] = f2bs(v.x); p[1] = f2bs(v.y); p[2] = f2bs(v.z); p[3] = f2bs(v.w);
      xw[lane + j * 64] = p;
#pragma unroll
      for (int e = 0; e < NE; ++e) {
        float4 w = s_rw4[e * 256 + lane + j * 64];
        a[e] = fmaf(v.x, w.x, fmaf(v.y, w.y, fmaf(v.z, w.z, fmaf(v.w, w.w, a[e]))));
      }
    }
#pragma unroll
    for (int off = 32; off > 0; off >>= 1) {
#pragma unroll
      for (int e = 0; e < NE; ++e) a[e] += __shfl_xor(a[e], off, 64);
    }
    if (lane == 0) {
      float l[NE];
#pragma unroll
      for (int e = 0; e < NE; ++e) l[e] = a[e] + rb[e];
      int e0 = 0;
#pragma unroll
      for (int e = 1; e < NE; ++e) if (l[e] > l[e0]) e0 = e;
      int e1 = (e0 == 0) ? 1 : 0;
#pragma unroll
      for (int e = 0; e < NE; ++e) if (e != e0 && l[e] > l[e1]) e1 = e;
      float r = expf(l[e1] - l[e0]);   // <= 1
      float g0 = 1.f / (1.f + r);
      float g1 = 1.f - g0;
      int ai = (wave * 4 + i) * 2;
      int p0 = atomicAdd(&s_cnt[e0], 1);   // LDS atomic only
      int p1 = atomicAdd(&s_cnt[e1], 1);
      s_e[ai] = e0; s_g[ai] = g0; s_pos[ai] = p0;
      s_e[ai + 1] = e1; s_g[ai + 1] = g1; s_pos[ai + 1] = p1;
    }
  }
  __syncthreads();
  if (tid < NE) blk_cnt[blockIdx.x * NE + tid] = s_cnt[tid];
  if (tid < 32) {
    int s = blockIdx.x * 32 + tid;
    tmp_meta[s] = s_e[tid] | (s_pos[tid] << 3);
    tmp_gate[s] = s_g[tid];
  }
}

// ---------------- scan: exclusive prefix of blk_cnt per expert ----------------
__global__ __launch_bounds__(512) void scan_kernel(
    const int* __restrict__ blk_cnt, int* __restrict__ blk_base,
    int* __restrict__ counts) {
  const int e = threadIdx.x >> 6, lane = threadIdx.x & 63;
  int running = 0;
  for (int c = 0; c < ROUTER_BLOCKS / 64; ++c) {
    int v = blk_cnt[(c * 64 + lane) * NE + e];
    int incl = v;
#pragma unroll
    for (int off = 1; off < 64; off <<= 1) {
      int t = __shfl_up(incl, off, 64);
      if (lane >= off) incl += t;
    }
    blk_base[(c * 64 + lane) * NE + e] = running + incl - v;
    running += __shfl(incl, 63, 64);
  }
  if (lane == 0) counts[e] = running;
}

// ---------------- scatter: place entries/gates ----------------
__global__ __launch_bounds__(256) void scatter_kernel(
    const int* __restrict__ tmp_meta, const float* __restrict__ tmp_gate,
    const int* __restrict__ blk_base, int* __restrict__ entries,
    float* __restrict__ gates, int n_tok) {
  int s = blockIdx.x * 256 + threadIdx.x;       // slot in [0, 2*n_tok)
  int meta = tmp_meta[s];
  int e = meta & 7, pos = meta >> 3;
  int p = blk_base[(s >> 5) * NE + e] + pos;
  entries[e * n_tok + p] = ((s >> 1) << 1) | (s & 1);   // token*2 + slot parity
  gates[e * n_tok + p] = tmp_gate[s];
}

// ---------------- grouped gathered GEMM ----------------
// 256x128 tile, BK=64; 8 waves (4M x 2N) of 64x64 = 4x4 of 16x16x32 bf16.
// LDS: A[2][256][128B] = 64 KB + B[2][128][128B] = 32 KB -> 96 KB, 1 block/CU.
// Swizzle: row R physical chunk c holds logical chunk c^(R&7); gload source
// pre-swizzled (qsw), ds_read applies the same XOR (0 conflicts in R7).
__global__ __launch_bounds__(512, 2) void moe_gemm(
    const __hip_bfloat16* __restrict__ xb, const __hip_bfloat16* __restrict__ wb,
    const float* __restrict__ eb, const int* __restrict__ counts,
    const int* __restrict__ entries, const float* __restrict__ gates,
    __hip_bfloat16* __restrict__ y, int n_tok) {
  const int xcd = blockIdx.x & 7;
  const int j = blockIdx.x >> 3;                  // [0, 136)
  const int ct = j & 7;
  const int virt = xcd * RT_PER_XCD + (j >> 3);   // virtual row-tile id

  int e = -1, rt = 0, cnt = 0, acc_t = 0;
#pragma unroll
  for (int i = 0; i < NE; ++i) {
    int c = counts[i];
    int t = (c + BM - 1) / BM;
    if (e < 0 && virt < acc_t + t) { e = i; rt = virt - acc_t; cnt = c; }
    acc_t += t;
  }
  if (e < 0) return;

  __shared__ __align__(16) char smem[98304];      // 96 KB

  const int tid = threadIdx.x;
  const int l = tid & 63, w = tid >> 6;
  const int row0 = rt * BM;
  const int n0 = ct * BN;

  // ---- staging source pointers (pre-swizzled chunk within 8-chunk row) ----
  // Load j covers LDS row (tid>>3) + j*64, physical chunk tid&7, which holds
  // logical chunk (tid&7)^(row&7) = (l&7)^(l>>3)  (row&7 invariant of j).
  const int qsw = (l & 7) ^ (l >> 3);
  const __hip_bfloat16* aptr[4];
  const __hip_bfloat16* bptr[2];
#pragma unroll
  for (int i = 0; i < 4; ++i) {
    int R = (tid >> 3) + i * 64;                  // [0,256)
    int gr = row0 + R;
    int ent = (gr < cnt) ? entries[e * n_tok + gr] : 0;
    aptr[i] = xb + (size_t)(ent >> 1) * DIMS + qsw * 8;
  }
#pragma unroll
  for (int i = 0; i < 2; ++i) {
    int R = (tid >> 3) + i * 64;                  // [0,128)
    bptr[i] = wb + ((size_t)e << 20) + (size_t)(n0 + R) * DIMS + qsw * 8;
  }

  // ---- fragment read offsets (bytes within a buffer) ----
  const int fr = l & 15, quad = l >> 4;
  const int wr = w >> 1, wc = w & 1;              // 4 x 2 wave grid
  const int swz = (quad ^ (fr & 7)) << 4;         // chunk XOR on read side
  const int aoff0 = (wr * 64 + fr) * 128 + swz;   // + mt*2048; ks=1: ^64
  const int boff0 = (wc * 64 + fr) * 128 + swz;   // + nt*2048; ks=1: ^64

  auto stageA = [&](int buf, int kt) {            // 4 loads -> buf.A
    const int koff = kt * 64;
#pragma unroll
    for (int i = 0; i < 4; ++i)
      __builtin_amdgcn_global_load_lds(
          (gp_t)(aptr[i] + koff),
          (sp_t)(smem + buf * 32768 + tid * 16 + i * 8192), 16, 0, 0);
  };
  auto stageB = [&](int buf, int kt) {            // 2 loads -> buf.B
    const int koff = kt * 64;
#pragma unroll
    for (int i = 0; i < 2; ++i)
      __builtin_amdgcn_global_load_lds(
          (gp_t)(bptr[i] + koff),
          (sp_t)(smem + 65536 + buf * 16384 + tid * 16 + i * 8192), 16, 0, 0);
  };

  f32x4 acc[4][4] = {};

  // prologue: A(0),B(0),A(1) staged; wait A(0)+B(0) (leave A(1)'s 4 in flight)
  stageA(0, 0);
  stageB(0, 0);
  stageA(1, 1);
  asm volatile("s_waitcnt vmcnt(4)" ::: "memory");
  __builtin_amdgcn_s_barrier();

#pragma unroll 1
  for (int t = 0; t < 16; ++t) {
    const int cur = t & 1;
    const char* As = smem + cur * 32768;
    const char* Bs = smem + 65536 + cur * 16384;
    short8 af[4][2], bf[4][2];

    // ======== phase 0: read A(all) + B nt01; stage B(t+1); MFMA nt01 ========
#pragma unroll
    for (int mt = 0; mt < 4; ++mt) {
      af[mt][0] = *(const short8*)(As + aoff0 + mt * 2048);
      af[mt][1] = *(const short8*)(As + ((aoff0 + mt * 2048) ^ 64));
    }
#pragma unroll
    for (int nt = 0; nt < 2; ++nt) {
      bf[nt][0] = *(const short8*)(Bs + boff0 + nt * 2048);
      bf[nt][1] = *(const short8*)(Bs + ((boff0 + nt * 2048) ^ 64));
    }
    if (t + 1 < 16) stageB(cur ^ 1, t + 1);       // other buffer: no WAR hazard
    __builtin_amdgcn_s_barrier();
    asm volatile("s_waitcnt lgkmcnt(0)" ::: "memory");
    __builtin_amdgcn_sched_barrier(0);
    __builtin_amdgcn_s_setprio(1);
#pragma unroll
    for (int mt = 0; mt < 4; ++mt)
#pragma unroll
      for (int nt = 0; nt < 2; ++nt) {
        acc[mt][nt] = __builtin_amdgcn_mfma_f32_16x16x32_bf16(af[mt][0], bf[nt][0], acc[mt][nt], 0, 0, 0);
        acc[mt][nt] = __builtin_amdgcn_mfma_f32_16x16x32_bf16(af[mt][1], bf[nt][1], acc[mt][nt], 0, 0, 0);
      }
    __builtin_amdgcn_s_setprio(0);
    __builtin_amdgcn_s_barrier();                 // all A reads of tile t landed

    // ======== phase 1: read B nt23; stage A(t+2) over buf[cur].A; MFMA ========
#pragma unroll
    for (int nt = 2; nt < 4; ++nt) {
      bf[nt][0] = *(const short8*)(Bs + boff0 + nt * 2048);
      bf[nt][1] = *(const short8*)(Bs + ((boff0 + nt * 2048) ^ 64));
    }
    if (t + 2 < 16) stageA(cur, t + 2);           // safe: A region free after ph0
    __builtin_amdgcn_s_barrier();
    asm volatile("s_waitcnt lgkmcnt(0)" ::: "memory");
    __builtin_amdgcn_sched_barrier(0);
    __builtin_amdgcn_s_setprio(1);
#pragma unroll
    for (int mt = 0; mt < 4; ++mt)
#pragma unroll
      for (int nt = 2; nt < 4; ++nt) {
        acc[mt][nt] = __builtin_amdgcn_mfma_f32_16x16x32_bf16(af[mt][0], bf[nt][0], acc[mt][nt], 0, 0, 0);
        acc[mt][nt] = __builtin_amdgcn_mfma_f32_16x16x32_bf16(af[mt][1], bf[nt][1], acc[mt][nt], 0, 0, 0);
      }
    __builtin_amdgcn_s_setprio(0);
    // counted drain: queue = [A(t+1):4][B(t+1):2][A(t+2):4] -> keep newest 4
    if (t <= 13)      asm volatile("s_waitcnt vmcnt(4)" ::: "memory");
    else if (t == 14) asm volatile("s_waitcnt vmcnt(0)" ::: "memory");
    __builtin_amdgcn_s_barrier();
  }

  // ---- epilogue: C/D layout col=lane&15, row=(lane>>4)*4+reg ----
  float bias[4];
#pragma unroll
  for (int nt = 0; nt < 4; ++nt) bias[nt] = eb[e * DIMS + n0 + wc * 64 + nt * 16 + fr];
#pragma unroll
  for (int mt = 0; mt < 4; ++mt) {
#pragma unroll
    for (int r = 0; r < 4; ++r) {
      int m = wr * 64 + mt * 16 + quad * 4 + r;
      int gr = row0 + m;
      if (gr < cnt) {
        int ent = entries[e * n_tok + gr];
        float g = gates[e * n_tok + gr];
        __hip_bfloat16* yp = y + (size_t)ent * DIMS + n0 + wc * 64 + fr;
#pragma unroll
        for (int nt = 0; nt < 4; ++nt)
          yp[nt * 16] = __float2bfloat16(g * (acc[mt][nt][r] + bias[nt]));
      }
    }
  }
}

// ---------------- combine: out[n] = y[n,0] + y[n,1] ----------------
__global__ __launch_bounds__(256) void combine_kernel(const __hip_bfloat16* __restrict__ y,
                                                      float* __restrict__ out) {
  size_t idx = (size_t)blockIdx.x * 256 + threadIdx.x;  // one 8-wide chunk
  size_t n = idx >> 7;
  int c = (int)(idx & 127) << 3;
  short8 v0 = *(const short8*)(y + (n * 2) * DIMS + c);
  short8 v1 = *(const short8*)(y + (n * 2 + 1) * DIMS + c);
  float4 o0, o1;
  o0.x = b2f((unsigned short)v0[0]) + b2f((unsigned short)v1[0]);
  o0.y = b2f((unsigned short)v0[1]) + b2f((unsigned short)v1[1]);
  o0.z = b2f((unsigned short)v0[2]) + b2f((unsigned short)v1[2]);
  o0.w = b2f((unsigned short)v0[3]) + b2f((unsigned short)v1[3]);
  o1.x = b2f((unsigned short)v0[4]) + b2f((unsigned short)v1[4]);
  o1.y = b2f((unsigned short)v0[5]) + b2f((unsigned short)v1[5]);
  o1.z = b2f((unsigned short)v0[6]) + b2f((unsigned short)v1[6]);
  o1.w = b2f((unsigned short)v0[7]) + b2f((unsigned short)v1[7]);
  float* op = out + n * DIMS + c;
  ((float4*)op)[0] = o0;
  ((float4*)op)[1] = o1;
}

extern "C" void kernel_launch(void* const* d_in, const int* in_sizes, int n_in,
                              void* d_out, int out_size, void* d_ws, size_t ws_size,
                              hipStream_t stream) {
  const float* x  = (const float*)d_in[0];
  const float* rw = (const float*)d_in[1];
  const float* rb = (const float*)d_in[2];
  const float* ew = (const float*)d_in[3];
  const float* eb = (const float*)d_in[4];
  float* out = (float*)d_out;
  const int n_tok = in_sizes[0] / DIMS;  // 16384
  const int n_slot = 2 * n_tok;

  // workspace layout
  char* ws = (char*)d_ws;
  size_t off = 0;
  int* counts = (int*)ws;                      off += 256;
  int* blk_cnt = (int*)(ws + off);             off += (size_t)ROUTER_BLOCKS * NE * 4;
  int* blk_base = (int*)(ws + off);            off += (size_t)ROUTER_BLOCKS * NE * 4;
  int* tmp_meta = (int*)(ws + off);            off += (size_t)n_slot * 4;
  float* tmp_gate = (float*)(ws + off);        off += (size_t)n_slot * 4;
  __hip_bfloat16* xb = (__hip_bfloat16*)(ws + off); off += (size_t)n_tok * DIMS * 2;
  __hip_bfloat16* wb = (__hip_bfloat16*)(ws + off); off += (size_t)NE * DIMS * DIMS * 2;
  int*   entries = (int*)(ws + off);           off += (size_t)NE * n_tok * 4;
  float* gates   = (float*)(ws + off);         off += (size_t)NE * n_tok * 4;
  __hip_bfloat16* y = (__hip_bfloat16*)(ws + off); off += (size_t)n_slot * DIMS * 2;
  if (ws_size < off) return;  // signature: output stays exactly zero

  prep_kernel<<<ROUTER_BLOCKS + WCONV_BLOCKS, 256, 0, stream>>>(
      x, rw, rb, ew, xb, wb, blk_cnt, tmp_meta, tmp_gate, n_tok);
  scan_kernel<<<1, 512, 0, stream>>>(blk_cnt, blk_base, counts);
  scatter_kernel<<<n_slot / 256, 256, 0, stream>>>(
      tmp_meta, tmp_gate, blk_base, entries, gates, n_tok);
  moe_gemm<<<8 * RT_PER_XCD * 8, 512, 0, stream>>>(
      xb, wb, eb, counts, entries, gates, y, n_tok);
  combine_kernel<<<(unsigned)((size_t)n_tok * DIMS / 8 / 256), 256, 0, stream>>>(y, out);
}

// Round 5
// 273.390 us; speedup vs baseline: 1.2091x; 1.0687x over previous
//
#include <hip/hip_runtime.h>
#include <hip/hip_bf16.h>

// MoE: N=16384 tokens, D=1024, E=8 experts, top-2 routing.
// R10: R5 base (best measured: gemm 104us, total 273us) + minimal pipeline fix:
// A-staging double-buffered (16KB LDS), ONE raw s_barrier per K-step, and the
// A gather issued ONE STEP AHEAD so the per-step vmcnt(0) waits on pre-landed
// data instead of draining a just-issued gather (~600-900cy L3 latency for
// random-token rows). B loads placed before the A-prefetch issue with a
// sched_barrier so the compiler's bf-wait is a counted vmcnt(2), never
// draining the in-flight prefetch. Keeps 4 blocks/CU TLP (launch_bounds 256,4;
// VGPR budget unchanged) — the mechanism that made R5/m97-structure work and
// that all 512-thread redesigns (R6-R9) lost.
// prep/scan/scatter/combine verbatim R5 (wb fragment-major).

constexpr int DIMS = 1024;
constexpr int NE   = 8;
constexpr int ROUTER_BLOCKS = 1024;           // 16 tokens per block
constexpr int WCONV_BLOCKS  = NE * DIMS * DIMS / (8 * 256);  // 4096
constexpr int RT_PER_XCD = 33;                // 33*8 = 264 >= 256+8 row-tiles

typedef __attribute__((ext_vector_type(8))) short short8;
typedef __attribute__((ext_vector_type(4))) short short4_t;
typedef __attribute__((ext_vector_type(4))) float f32x4;

typedef const __attribute__((address_space(1))) void* gp_t;
typedef __attribute__((address_space(3))) void* sp_t;

__device__ __forceinline__ float b2f(unsigned short u) {
  union { unsigned int i; float f; } x; x.i = ((unsigned)u) << 16; return x.f;
}
__device__ __forceinline__ short f2bs(float f) {
  __hip_bfloat16 h = __float2bfloat16(f);
  return *(short*)&h;
}

// ---------------- prep: router blocks [0,1024) + wconv blocks [1024,5120) ----
// wconv writes wb FRAGMENT-MAJOR: chunk g = ((e*64+nb)*32+kc)*64+l holds
// W[e][n=nb*16+(l&15)][d = kc*32+(l>>4)*8 .. +8] as 8 bf16 (16B).
// router: NO global atomics — writes per-block counts + per-slot meta.
__global__ __launch_bounds__(256) void prep_kernel(
    const float* __restrict__ x, const float* __restrict__ rw,
    const float* __restrict__ rb, const float* __restrict__ ew,
    __hip_bfloat16* __restrict__ xb, __hip_bfloat16* __restrict__ wb,
    int* __restrict__ blk_cnt, int* __restrict__ tmp_meta,
    float* __restrict__ tmp_gate, int n_tok) {
  const int tid = threadIdx.x;

  if ((int)blockIdx.x >= ROUTER_BLOCKS) {
    unsigned g = (unsigned)(blockIdx.x - ROUTER_BLOCKS) * 256 + tid;
    int l  = g & 63;
    int kc = (g >> 6) & 31;
    int nb = (g >> 11) & 63;
    int e  = g >> 17;
    int row = nb * 16 + (l & 15);
    int kb  = kc * 32 + ((l >> 4) << 3);
    const float4* src = (const float4*)(ew + ((size_t)e << 20) + (size_t)row * DIMS + kb);
    float4 a = src[0], b = src[1];
    union { __hip_bfloat16 h[8]; float4 f; } u;
    u.h[0] = __float2bfloat16(a.x); u.h[1] = __float2bfloat16(a.y);
    u.h[2] = __float2bfloat16(a.z); u.h[3] = __float2bfloat16(a.w);
    u.h[4] = __float2bfloat16(b.x); u.h[5] = __float2bfloat16(b.y);
    u.h[6] = __float2bfloat16(b.z); u.h[7] = __float2bfloat16(b.w);
    ((float4*)wb)[g] = u.f;
    return;
  }

  // ---- router role: 16 tokens/block, wave-per-token, float4 vectorized ----
  __shared__ float s_rw[NE * DIMS];   // 32 KB
  __shared__ int s_cnt[NE];
  __shared__ int s_e[32];
  __shared__ float s_g[32];
  __shared__ int s_pos[32];

  const float4* rw4g = (const float4*)rw;
  float4* s4 = (float4*)s_rw;
  for (int i = tid; i < NE * DIMS / 4; i += 256) s4[i] = rw4g[i];
  if (tid < NE) s_cnt[tid] = 0;
  __syncthreads();

  const float4* s_rw4 = (const float4*)s_rw;
  const int wave = tid >> 6, lane = tid & 63;
  for (int i = 0; i < 4; ++i) {
    int t = blockIdx.x * 16 + wave * 4 + i;
    const float4* xr = (const float4*)(x + (size_t)t * DIMS);
    short4_t* xw = (short4_t*)(xb + (size_t)t * DIMS);
    float a[NE];
#pragma unroll
    for (int e = 0; e < NE; ++e) a[e] = 0.f;
#pragma unroll
    for (int j = 0; j < 4; ++j) {
      float4 v = xr[lane + j * 64];
      short4_t p;
      p[0] = f2bs(v.x); p[1] = f2bs(v.y); p[2] = f2bs(v.z); p[3] = f2bs(v.w);
      xw[lane + j * 64] = p;
#pragma unroll
      for (int e = 0; e < NE; ++e) {
        float4 w = s_rw4[e * 256 + lane + j * 64];
        a[e] = fmaf(v.x, w.x, fmaf(v.y, w.y, fmaf(v.z, w.z, fmaf(v.w, w.w, a[e]))));
      }
    }
#pragma unroll
    for (int off = 32; off > 0; off >>= 1) {
#pragma unroll
      for (int e = 0; e < NE; ++e) a[e] += __shfl_xor(a[e], off, 64);
    }
    if (lane == 0) {
      float l[NE];
#pragma unroll
      for (int e = 0; e < NE; ++e) l[e] = a[e] + rb[e];
      int e0 = 0;
#pragma unroll
      for (int e = 1; e < NE; ++e) if (l[e] > l[e0]) e0 = e;
      int e1 = (e0 == 0) ? 1 : 0;
#pragma unroll
      for (int e = 0; e < NE; ++e) if (e != e0 && l[e] > l[e1]) e1 = e;
      float r = expf(l[e1] - l[e0]);   // <= 1
      float g0 = 1.f / (1.f + r);
      float g1 = 1.f - g0;
      int ai = (wave * 4 + i) * 2;
      int p0 = atomicAdd(&s_cnt[e0], 1);   // LDS atomic only
      int p1 = atomicAdd(&s_cnt[e1], 1);
      s_e[ai] = e0; s_g[ai] = g0; s_pos[ai] = p0;
      s_e[ai + 1] = e1; s_g[ai + 1] = g1; s_pos[ai + 1] = p1;
    }
  }
  __syncthreads();
  if (tid < NE) blk_cnt[blockIdx.x * NE + tid] = s_cnt[tid];
  if (tid < 32) {
    int s = blockIdx.x * 32 + tid;
    tmp_meta[s] = s_e[tid] | (s_pos[tid] << 3);
    tmp_gate[s] = s_g[tid];
  }
}

// ---------------- scan: exclusive prefix of blk_cnt per expert ----------------
__global__ __launch_bounds__(512) void scan_kernel(
    const int* __restrict__ blk_cnt, int* __restrict__ blk_base,
    int* __restrict__ counts) {
  const int e = threadIdx.x >> 6, lane = threadIdx.x & 63;
  int running = 0;
  for (int c = 0; c < ROUTER_BLOCKS / 64; ++c) {
    int v = blk_cnt[(c * 64 + lane) * NE + e];
    int incl = v;
#pragma unroll
    for (int off = 1; off < 64; off <<= 1) {
      int t = __shfl_up(incl, off, 64);
      if (lane >= off) incl += t;
    }
    blk_base[(c * 64 + lane) * NE + e] = running + incl - v;
    running += __shfl(incl, 63, 64);
  }
  if (lane == 0) counts[e] = running;
}

// ---------------- scatter: place entries/gates ----------------
__global__ __launch_bounds__(256) void scatter_kernel(
    const int* __restrict__ tmp_meta, const float* __restrict__ tmp_gate,
    const int* __restrict__ blk_base, int* __restrict__ entries,
    float* __restrict__ gates, int n_tok) {
  int s = blockIdx.x * 256 + threadIdx.x;       // slot in [0, 2*n_tok)
  int meta = tmp_meta[s];
  int e = meta & 7, pos = meta >> 3;
  int p = blk_base[(s >> 5) * NE + e] + pos;
  entries[e * n_tok + p] = ((s >> 1) << 1) | (s & 1);   // token*2 + slot parity
  gates[e * n_tok + p] = tmp_gate[s];
}

// ---------------- grouped gathered GEMM ----------------
// 128x128 tile, BK=32; 4 waves (2x2) of 64x64 = 4x4 of 16x16x32 bf16.
// A: gload_lds, DOUBLE-buffered (2x8KB), issued ONE K-step ahead.
// B: direct global from fragment-major wb (XCD-L2 resident).
// Per K-step: vmcnt(0) [pre-landed A(t)] -> s_barrier -> bf loads ->
// schedbar -> gload A(t+1) -> buf^1 -> ds_read af -> 16 MFMA
// (compiler emits vmcnt(2) for bf: A(t+1) stays in flight). One barrier/step.
__global__ __launch_bounds__(256, 4) void moe_gemm(
    const __hip_bfloat16* __restrict__ xb, const __hip_bfloat16* __restrict__ wb,
    const float* __restrict__ eb, const int* __restrict__ counts,
    const int* __restrict__ entries, const float* __restrict__ gates,
    __hip_bfloat16* __restrict__ y, int n_tok) {
  const int xcd = blockIdx.x & 7;
  const int j = blockIdx.x >> 3;
  const int ct = j & 7;
  const int virt = xcd * RT_PER_XCD + (j >> 3);   // virtual row-tile id

  // map virt -> (expert, row-tile) from device-side counts
  int e = -1, rt = 0, cnt = 0, acc_t = 0;
#pragma unroll
  for (int i = 0; i < NE; ++i) {
    int c = counts[i];
    int t = (c + 127) >> 7;
    if (e < 0 && virt < acc_t + t) { e = i; rt = virt - acc_t; cnt = c; }
    acc_t += t;
  }
  if (e < 0) return;

  __shared__ __hip_bfloat16 As[2][128 * 32];  // 16 KB double-buffered

  const int tid = threadIdx.x;
  const int lane = tid & 63, wave = tid >> 6;
  const int row0 = rt * 128;
  const int n0 = ct * 128;

  // A staging: thread t -> LDS slots t, t+256 (16B chunks); slot (srow, q)
  // holds global chunk kcs = q ^ (srow&3).
  const int srow = tid >> 2;
  const int kcs = (tid & 3) ^ (srow & 3);
  const int kcol = kcs * 8;
  int gr0 = row0 + srow, gr1 = row0 + srow + 64;
  int ent0 = (gr0 < cnt) ? entries[e * n_tok + gr0] : 0;
  int ent1 = (gr1 < cnt) ? entries[e * n_tok + gr1] : 0;
  const __hip_bfloat16* ap0 = xb + (size_t)(ent0 >> 1) * DIMS + kcol;
  const __hip_bfloat16* ap1 = xb + (size_t)(ent1 >> 1) * DIMS + kcol;

  const int wm = (wave & 1) * 64, wn = (wave >> 1) * 64;
  const int fr = lane & 15, quad = lane >> 4;
  const int swo = (quad ^ (fr & 3)) * 8;   // swizzled read offset

  // B fragment-major: chunk g = ((e*64+nb)*32+kc)*64 + lane
  const short8* wb8 = (const short8*)wb;
  const size_t bbase = (((size_t)e * 64 + ((n0 + wn) >> 4)) * 32) * 64 + lane;

  f32x4 acc[4][4] = {};

  // prologue: stage A(0) into buf 0 (in flight across mapping/addr setup)
  __builtin_amdgcn_global_load_lds((gp_t)(ap0), (sp_t)(&As[0][tid * 8]), 16, 0, 0);
  __builtin_amdgcn_global_load_lds((gp_t)(ap1), (sp_t)(&As[0][(tid + 256) * 8]), 16, 0, 0);

#pragma unroll 1
  for (int ks = 0; ks < 32; ++ks) {
    const int cur = ks & 1;
    // A(ks) was issued one step ago -> vmcnt(0) is (near-)pre-landed.
    // Queue holds ONLY A(ks) here: bf(ks-1) retired before last step's MFMA,
    // and bf(ks)/A(ks+1) are issued below.
    asm volatile("s_waitcnt vmcnt(0)" ::: "memory");
    __builtin_amdgcn_s_barrier();               // A(ks) visible to all waves
    __builtin_amdgcn_sched_barrier(0);

    // B(ks): direct global (L2-resident), BEFORE the A-prefetch issue so the
    // compiler's wait before MFMA is a counted vmcnt(2), not a drain.
    short8 bf[4];
#pragma unroll
    for (int nt = 0; nt < 4; ++nt)
      bf[nt] = wb8[bbase + (size_t)nt * 2048 + ks * 64];
    __builtin_amdgcn_sched_barrier(0);

    // A(ks+1) -> other buffer. Safe: every wave passing this step's barrier
    // has retired its ds_reads of buf[cur^1] (consumed by last step's MFMAs).
    if (ks < 31) {
      __builtin_amdgcn_global_load_lds((gp_t)(ap0 + (ks + 1) * 32),
                                       (sp_t)(&As[cur ^ 1][tid * 8]), 16, 0, 0);
      __builtin_amdgcn_global_load_lds((gp_t)(ap1 + (ks + 1) * 32),
                                       (sp_t)(&As[cur ^ 1][(tid + 256) * 8]), 16, 0, 0);
    }

    short8 af[4];
#pragma unroll
    for (int mt = 0; mt < 4; ++mt)
      af[mt] = *(const short8*)&As[cur][(wm + mt * 16 + fr) * 32 + swo];
#pragma unroll
    for (int mt = 0; mt < 4; ++mt)
#pragma unroll
      for (int nt = 0; nt < 4; ++nt)
        acc[mt][nt] = __builtin_amdgcn_mfma_f32_16x16x32_bf16(af[mt], bf[nt], acc[mt][nt], 0, 0, 0);
    // no trailing barrier: next step's barrier orders buf reuse.
  }

  // epilogue: C/D layout col=lane&15, row=(lane>>4)*4+reg. Store gated y (bf16).
  float bias[4];
#pragma unroll
  for (int nt = 0; nt < 4; ++nt) bias[nt] = eb[e * DIMS + n0 + wn + nt * 16 + fr];
#pragma unroll
  for (int mt = 0; mt < 4; ++mt) {
#pragma unroll
    for (int r = 0; r < 4; ++r) {
      int m = wm + mt * 16 + quad * 4 + r;
      int gr = row0 + m;
      if (gr < cnt) {
        int ent = entries[e * n_tok + gr];
        float g = gates[e * n_tok + gr];
        __hip_bfloat16* yp = y + (size_t)ent * DIMS + n0 + wn + fr;
#pragma unroll
        for (int nt = 0; nt < 4; ++nt)
          yp[nt * 16] = __float2bfloat16(g * (acc[mt][nt][r] + bias[nt]));
      }
    }
  }
}

// ---------------- combine: out[n] = y[n,0] + y[n,1] ----------------
__global__ __launch_bounds__(256) void combine_kernel(const __hip_bfloat16* __restrict__ y,
                                                      float* __restrict__ out) {
  size_t idx = (size_t)blockIdx.x * 256 + threadIdx.x;  // one 8-wide chunk
  size_t n = idx >> 7;
  int c = (int)(idx & 127) << 3;
  short8 v0 = *(const short8*)(y + (n * 2) * DIMS + c);
  short8 v1 = *(const short8*)(y + (n * 2 + 1) * DIMS + c);
  float4 o0, o1;
  o0.x = b2f((unsigned short)v0[0]) + b2f((unsigned short)v1[0]);
  o0.y = b2f((unsigned short)v0[1]) + b2f((unsigned short)v1[1]);
  o0.z = b2f((unsigned short)v0[2]) + b2f((unsigned short)v1[2]);
  o0.w = b2f((unsigned short)v0[3]) + b2f((unsigned short)v1[3]);
  o1.x = b2f((unsigned short)v0[4]) + b2f((unsigned short)v1[4]);
  o1.y = b2f((unsigned short)v0[5]) + b2f((unsigned short)v1[5]);
  o1.z = b2f((unsigned short)v0[6]) + b2f((unsigned short)v1[6]);
  o1.w = b2f((unsigned short)v0[7]) + b2f((unsigned short)v1[7]);
  float* op = out + n * DIMS + c;
  ((float4*)op)[0] = o0;
  ((float4*)op)[1] = o1;
}

extern "C" void kernel_launch(void* const* d_in, const int* in_sizes, int n_in,
                              void* d_out, int out_size, void* d_ws, size_t ws_size,
                              hipStream_t stream) {
  const float* x  = (const float*)d_in[0];
  const float* rw = (const float*)d_in[1];
  const float* rb = (const float*)d_in[2];
  const float* ew = (const float*)d_in[3];
  const float* eb = (const float*)d_in[4];
  float* out = (float*)d_out;
  const int n_tok = in_sizes[0] / DIMS;  // 16384
  const int n_slot = 2 * n_tok;

  // workspace layout
  char* ws = (char*)d_ws;
  size_t off = 0;
  int* counts = (int*)ws;                      off += 256;
  int* blk_cnt = (int*)(ws + off);             off += (size_t)ROUTER_BLOCKS * NE * 4;
  int* blk_base = (int*)(ws + off);            off += (size_t)ROUTER_BLOCKS * NE * 4;
  int* tmp_meta = (int*)(ws + off);            off += (size_t)n_slot * 4;
  float* tmp_gate = (float*)(ws + off);        off += (size_t)n_slot * 4;
  __hip_bfloat16* xb = (__hip_bfloat16*)(ws + off); off += (size_t)n_tok * DIMS * 2;
  __hip_bfloat16* wb = (__hip_bfloat16*)(ws + off); off += (size_t)NE * DIMS * DIMS * 2;
  int*   entries = (int*)(ws + off);           off += (size_t)NE * n_tok * 4;
  float* gates   = (float*)(ws + off);         off += (size_t)NE * n_tok * 4;
  __hip_bfloat16* y = (__hip_bfloat16*)(ws + off); off += (size_t)n_slot * DIMS * 2;
  if (ws_size < off) return;  // signature: output stays exactly zero

  prep_kernel<<<ROUTER_BLOCKS + WCONV_BLOCKS, 256, 0, stream>>>(
      x, rw, rb, ew, xb, wb, blk_cnt, tmp_meta, tmp_gate, n_tok);
  scan_kernel<<<1, 512, 0, stream>>>(blk_cnt, blk_base, counts);
  scatter_kernel<<<n_slot / 256, 256, 0, stream>>>(
      tmp_meta, tmp_gate, blk_base, entries, gates, n_tok);
  moe_gemm<<<8 * RT_PER_XCD * 8, 256, 0, stream>>>(
      xb, wb, eb, counts, entries, gates, y, n_tok);
  combine_kernel<<<(unsigned)((size_t)n_tok * DIMS / 8 / 256), 256, 0, stream>>>(y, out);
}